// Round 1
// 474.463 us; speedup vs baseline: 1.1937x; 1.1937x over previous
//
#include <hip/hip_runtime.h>
#include <hip/hip_fp16.h>

#define NEG 0.2f

typedef _Float16 f16x8 __attribute__((ext_vector_type(8)));
typedef _Float16 f16x2 __attribute__((ext_vector_type(2)));
typedef float    f32x4 __attribute__((ext_vector_type(4)));

__device__ __forceinline__ float fdot2h(__half2 a, __half2 b, float c) {
    return __builtin_amdgcn_fdot2(__builtin_bit_cast(f16x2, a),
                                  __builtin_bit_cast(f16x2, b), c, false);
}

__device__ __forceinline__ __half2 u2h2(unsigned int u) {
    return __builtin_bit_cast(__half2, u);
}

// packed half2 max via v_pk_max_f16 (ROCm header lacks __hmax2 on this toolchain)
__device__ __forceinline__ __half2 hmax2(__half2 a, __half2 b) {
    unsigned int ua = __builtin_bit_cast(unsigned int, a);
    unsigned int ub = __builtin_bit_cast(unsigned int, b);
    unsigned int ud;
    asm("v_pk_max_f16 %0, %1, %2" : "=v"(ud) : "v"(ua), "v"(ub));
    return __builtin_bit_cast(__half2, ud);
}

// ---------------- MFMA GEMM: Y = half(X[N,128] @ [Wl|Wr] + bias) ----------------
template<int CPW, bool IN_F16>
__global__ __launch_bounds__(256) void mfma_gemm_k(
    const float* __restrict__ Xf, const __half* __restrict__ Xh,
    const float* __restrict__ Wl, const float* __restrict__ bl,
    const float* __restrict__ Wr, const float* __restrict__ br,
    __half* __restrict__ YL, __half* __restrict__ YR, int nrows)
{
    __shared__ _Float16 Xs[128 * 136];
    __shared__ _Float16 Ws[128 * 136];

    const int t    = threadIdx.x;
    const int row0 = blockIdx.x * 128;
    const int c0   = blockIdx.y * 128;

    if constexpr (IN_F16) {
        for (int i = t; i < 128 * 16; i += 256) {
            int r = i >> 4, c = i & 15;
            int gr = row0 + r;
            uint4 v = make_uint4(0u, 0u, 0u, 0u);
            if (gr < nrows) v = ((const uint4*)Xh)[(long)gr * 16 + c];
            *(uint4*)&Xs[r * 136 + c * 8] = v;
        }
    } else {
        for (int i = t; i < 128 * 16; i += 256) {
            int r = i >> 4, c = i & 15;
            int gr = row0 + r;
            float4 a = make_float4(0.f,0.f,0.f,0.f), b4 = make_float4(0.f,0.f,0.f,0.f);
            if (gr < nrows) {
                a  = ((const float4*)Xf)[(long)gr * 32 + c * 2];
                b4 = ((const float4*)Xf)[(long)gr * 32 + c * 2 + 1];
            }
            _Float16 h[8] = {(_Float16)a.x,(_Float16)a.y,(_Float16)a.z,(_Float16)a.w,
                             (_Float16)b4.x,(_Float16)b4.y,(_Float16)b4.z,(_Float16)b4.w};
            *(f16x8*)&Xs[r * 136 + c * 8] = *(f16x8*)h;
        }
    }

    for (int i = t; i < 128 * 128; i += 256) {
        int k = i >> 7, n = i & 127;
        int gc = c0 + n;
        const float* Wp = (gc >= CPW) ? Wr : Wl;
        int lc = gc & (CPW - 1);
        Ws[n * 136 + k] = (_Float16)Wp[(long)k * CPW + lc];
    }
    __syncthreads();

    const int lane  = t & 63;
    const int wv    = t >> 6;
    const int m     = lane & 15;
    const int quad  = lane >> 4;
    const int rbase = wv * 32;

    f16x8 Af[2][4];
    #pragma unroll
    for (int rt = 0; rt < 2; ++rt)
        #pragma unroll
        for (int ks = 0; ks < 4; ++ks)
            Af[rt][ks] = *(const f16x8*)&Xs[(rbase + rt * 16 + m) * 136 + ks * 32 + quad * 8];

    f32x4 acc[2][8];
    #pragma unroll
    for (int rt = 0; rt < 2; ++rt)
        #pragma unroll
        for (int ct = 0; ct < 8; ++ct)
            acc[rt][ct] = (f32x4){0.f, 0.f, 0.f, 0.f};

    #pragma unroll
    for (int ct = 0; ct < 8; ++ct) {
        #pragma unroll
        for (int ks = 0; ks < 4; ++ks) {
            f16x8 Bf = *(const f16x8*)&Ws[(ct * 16 + m) * 136 + ks * 32 + quad * 8];
            acc[0][ct] = __builtin_amdgcn_mfma_f32_16x16x32_f16(Af[0][ks], Bf, acc[0][ct], 0, 0, 0);
            acc[1][ct] = __builtin_amdgcn_mfma_f32_16x16x32_f16(Af[1][ks], Bf, acc[1][ct], 0, 0, 0);
        }
    }

    #pragma unroll
    for (int ct = 0; ct < 8; ++ct) {
        int gc = c0 + ct * 16 + m;
        int which = gc / CPW;
        int lc = gc % CPW;
        _Float16* Y = (_Float16*)(which ? YR : YL);
        float bv = (which ? br : bl)[lc];
        #pragma unroll
        for (int rt = 0; rt < 2; ++rt) {
            int rr = row0 + rbase + rt * 16 + quad * 4;
            #pragma unroll
            for (int g = 0; g < 4; ++g) {
                int r = rr + g;
                if (r < nrows)
                    Y[(long)r * CPW + lc] = (_Float16)(acc[rt][ct][g] + bv);
            }
        }
    }
}

// ---------------- CSR build ----------------
// Pass A: rank of each edge within its dst bucket (atomic+ret, coalesced store).
__global__ __launch_bounds__(256) void rank_k(
    const int* __restrict__ ei, int* __restrict__ cnt, int* __restrict__ rnk,
    int E0, int N)
{
    int e = blockIdx.x * 1024 + threadIdx.x;
    int ET = E0 + N;
    #pragma unroll
    for (int u = 0; u < 4; ++u, e += 256) {
        if (e < ET) {
            int dst = (e < E0) ? ei[E0 + e] : (e - E0);
            rnk[e] = atomicAdd(&cnt[dst], 1);
        }
    }
}

__global__ __launch_bounds__(256) void scan1_k(
    const int* __restrict__ cnt, int* __restrict__ loc, int* __restrict__ bsum, int n)
{
    __shared__ int wsum[4];
    int t = threadIdx.x;
    int i0 = blockIdx.x * 1024 + t * 4;
    int4 v;
    v.x = (i0 + 0 < n) ? cnt[i0 + 0] : 0;
    v.y = (i0 + 1 < n) ? cnt[i0 + 1] : 0;
    v.z = (i0 + 2 < n) ? cnt[i0 + 2] : 0;
    v.w = (i0 + 3 < n) ? cnt[i0 + 3] : 0;
    int tsum = v.x + v.y + v.z + v.w;
    int incl = tsum;
    #pragma unroll
    for (int s = 1; s < 64; s <<= 1) {
        int u = __shfl_up(incl, s, 64);
        if ((t & 63) >= s) incl += u;
    }
    int wid = t >> 6;
    if ((t & 63) == 63) wsum[wid] = incl;
    __syncthreads();
    int woff = 0;
    #pragma unroll
    for (int w = 0; w < 4; ++w) if (w < wid) woff += wsum[w];
    int ex = woff + incl - tsum;
    if (i0 + 0 < n) loc[i0 + 0] = ex;
    if (i0 + 1 < n) loc[i0 + 1] = ex + v.x;
    if (i0 + 2 < n) loc[i0 + 2] = ex + v.x + v.y;
    if (i0 + 3 < n) loc[i0 + 3] = ex + v.x + v.y + v.z;
    if (t == 255) bsum[blockIdx.x] = woff + incl;
}

__global__ void scan2_k(const int* __restrict__ bsum, int* __restrict__ bcarry,
                        int M, int* __restrict__ total_out)
{
    int lane = threadIdx.x;
    int carry = 0;
    for (int base = 0; base < M; base += 64) {
        int i = base + lane;
        int v = (i < M) ? bsum[i] : 0;
        int incl = v;
        #pragma unroll
        for (int s = 1; s < 64; s <<= 1) {
            int u = __shfl_up(incl, s, 64);
            if (lane >= s) incl += u;
        }
        if (i < M) bcarry[i] = carry + incl - v;
        carry += __shfl(incl, 63, 64);
    }
    if (lane == 0) *total_out = carry;
}

__global__ __launch_bounds__(256) void scan3_k(
    int* __restrict__ off, const int* __restrict__ bcarry, int n)
{
    int i = blockIdx.x * 256 + threadIdx.x;
    if (i >= n) return;
    off[i] += bcarry[i >> 10];
}

// Pass C: scatter src into its CSR slot (no atomics, full MLP).
__global__ __launch_bounds__(256) void scatter_k(
    const int* __restrict__ ei, const int* __restrict__ off_,
    const int* __restrict__ rnk, int* __restrict__ srcs, int E0, int N)
{
    int e = blockIdx.x * 1024 + threadIdx.x;
    int ET = E0 + N;
    #pragma unroll
    for (int u = 0; u < 4; ++u, e += 256) {
        if (e < ET) {
            int src = (e < E0) ? ei[e]      : (e - E0);
            int dst = (e < E0) ? ei[E0 + e] : (e - E0);
            srcs[off_[dst] + rnk[e]] = src;
        }
    }
}

// ---------------- fused score + softmax + aggregation, per dst node ----------------
// Layer 1: H=4, C=32. One wave per dst node; 4 edge-slots x 16 lanes;
// each lane owns 8 consecutive feats (head = sub>>2). Score reduce = 2 shuffles
// (xor 1,2 within the 4-lane head group); 4 edges per loop iteration.
template<bool RELU>
__global__ __launch_bounds__(256) void fused128_k(
    const __half* __restrict__ XL, const __half* __restrict__ XR,
    const float* __restrict__ ATT, const int* __restrict__ srcs,
    const int* __restrict__ off, const float* __restrict__ bias,
    __half* __restrict__ OUT, int N)
{
    int d = blockIdx.x * 4 + (threadIdx.x >> 6);
    if (d >= N) return;
    const int lane = threadIdx.x & 63;
    const int sub  = lane & 15;   // feats 8*sub .. 8*sub+7 (all in head sub>>2)
    const int grp  = lane >> 4;   // edge slot 0..3
    int a = off[d], b = off[d + 1];

    uint4 ur = *(const uint4*)(XR + (long)d * 128 + sub * 8);
    __half2 xr[4] = { u2h2(ur.x), u2h2(ur.y), u2h2(ur.z), u2h2(ur.w) };
    float4 at0f = ((const float4*)ATT)[sub * 2];
    float4 at1f = ((const float4*)ATT)[sub * 2 + 1];
    __half2 at[4] = { __floats2half2_rn(at0f.x, at0f.y), __floats2half2_rn(at0f.z, at0f.w),
                      __floats2half2_rn(at1f.x, at1f.y), __floats2half2_rn(at1f.z, at1f.w) };
    const __half2 neg2 = __float2half2_rn(NEG);

    float l = 0.f;
    float accv[8] = {0.f,0.f,0.f,0.f,0.f,0.f,0.f,0.f};

    for (int e0 = a; e0 < b; e0 += 4) {
        int e = e0 + grp;
        bool valid = e < b;
        int s = srcs[valid ? e : b - 1];
        uint4 ux = *(const uint4*)(XL + (long)s * 128 + sub * 8);
        __half2 x0 = u2h2(ux.x), x1 = u2h2(ux.y), x2 = u2h2(ux.z), x3 = u2h2(ux.w);

        __half2 s0 = __hadd2(x0, xr[0]);
        __half2 s1 = __hadd2(x1, xr[1]);
        __half2 s2 = __hadd2(x2, xr[2]);
        __half2 s3 = __hadd2(x3, xr[3]);
        __half2 q0 = hmax2(s0, __hmul2(s0, neg2));
        __half2 q1 = hmax2(s1, __hmul2(s1, neg2));
        __half2 q2 = hmax2(s2, __hmul2(s2, neg2));
        __half2 q3 = hmax2(s3, __hmul2(s3, neg2));
        float p = fdot2h(q0, at[0], 0.f);
        p = fdot2h(q1, at[1], p);
        p = fdot2h(q2, at[2], p);
        p = fdot2h(q3, at[3], p);
        // reduce over 4-lane head group
        p += __shfl_xor(p, 1, 64);
        p += __shfl_xor(p, 2, 64);
        float ex = valid ? __expf(p) : 0.f;
        l += ex;
        float2 f0 = __half22float2(x0), f1 = __half22float2(x1);
        float2 f2 = __half22float2(x2), f3 = __half22float2(x3);
        accv[0] += ex * f0.x; accv[1] += ex * f0.y;
        accv[2] += ex * f1.x; accv[3] += ex * f1.y;
        accv[4] += ex * f2.x; accv[5] += ex * f2.y;
        accv[6] += ex * f3.x; accv[7] += ex * f3.y;
    }

    // combine the 4 edge slots (lane bits 4,5)
    l += __shfl_xor(l, 16, 64);
    l += __shfl_xor(l, 32, 64);
    #pragma unroll
    for (int j = 0; j < 8; ++j) {
        accv[j] += __shfl_xor(accv[j], 16, 64);
        accv[j] += __shfl_xor(accv[j], 32, 64);
    }

    if (grp == 0) {
        float inv = 1.f / l;
        float4 b0 = ((const float4*)bias)[sub * 2];
        float4 b1 = ((const float4*)bias)[sub * 2 + 1];
        float o[8] = { accv[0]*inv + b0.x, accv[1]*inv + b0.y,
                       accv[2]*inv + b0.z, accv[3]*inv + b0.w,
                       accv[4]*inv + b1.x, accv[5]*inv + b1.y,
                       accv[6]*inv + b1.z, accv[7]*inv + b1.w };
        if constexpr (RELU) {
            #pragma unroll
            for (int j = 0; j < 8; ++j) o[j] = fmaxf(o[j], 0.f);
        }
        uint4 uo;
        uo.x = __builtin_bit_cast(unsigned int, __floats2half2_rn(o[0], o[1]));
        uo.y = __builtin_bit_cast(unsigned int, __floats2half2_rn(o[2], o[3]));
        uo.z = __builtin_bit_cast(unsigned int, __floats2half2_rn(o[4], o[5]));
        uo.w = __builtin_bit_cast(unsigned int, __floats2half2_rn(o[6], o[7]));
        *(uint4*)(OUT + (long)d * 128 + sub * 8) = uo;
    }
}

// Layer 2: H=1, C=64. One wave per dst node; 4 edge-slots x 16 lanes;
// each lane owns 4 consecutive feats. Score reduce = 4 shuffles over the
// 16-lane group; 4 edges per loop iteration.
template<bool RELU>
__global__ __launch_bounds__(256) void fused64_k(
    const __half* __restrict__ XL, const __half* __restrict__ XR,
    const float* __restrict__ ATT, const int* __restrict__ srcs,
    const int* __restrict__ off, const float* __restrict__ bias,
    float* __restrict__ OUT, int N)
{
    int d = blockIdx.x * 4 + (threadIdx.x >> 6);
    if (d >= N) return;
    const int lane = threadIdx.x & 63;
    const int sub  = lane & 15;   // feats 4*sub .. 4*sub+3
    const int grp  = lane >> 4;   // edge slot 0..3
    int a = off[d], b = off[d + 1];

    uint2 ur = *(const uint2*)(XR + (long)d * 64 + sub * 4);
    __half2 xr0 = u2h2(ur.x), xr1 = u2h2(ur.y);
    float4 atf = ((const float4*)ATT)[sub];
    __half2 at0 = __floats2half2_rn(atf.x, atf.y);
    __half2 at1 = __floats2half2_rn(atf.z, atf.w);
    const __half2 neg2 = __float2half2_rn(NEG);

    float l = 0.f;
    float4 acc = make_float4(0.f, 0.f, 0.f, 0.f);

    for (int e0 = a; e0 < b; e0 += 4) {
        int e = e0 + grp;
        bool valid = e < b;
        int s = srcs[valid ? e : b - 1];
        uint2 ux = *(const uint2*)(XL + (long)s * 64 + sub * 4);
        __half2 x0 = u2h2(ux.x), x1 = u2h2(ux.y);

        __half2 s0 = __hadd2(x0, xr0);
        __half2 s1 = __hadd2(x1, xr1);
        __half2 q0 = hmax2(s0, __hmul2(s0, neg2));
        __half2 q1 = hmax2(s1, __hmul2(s1, neg2));
        float p = fdot2h(q1, at1, fdot2h(q0, at0, 0.f));
        // reduce over the 16-lane group
        p += __shfl_xor(p, 1, 64);
        p += __shfl_xor(p, 2, 64);
        p += __shfl_xor(p, 4, 64);
        p += __shfl_xor(p, 8, 64);
        float ex = valid ? __expf(p) : 0.f;
        float2 f0 = __half22float2(x0), f1 = __half22float2(x1);
        l += ex;
        acc.x += ex * f0.x; acc.y += ex * f0.y;
        acc.z += ex * f1.x; acc.w += ex * f1.y;
    }

    // combine the 4 edge slots
    l += __shfl_xor(l, 16, 64);
    l += __shfl_xor(l, 32, 64);
    acc.x += __shfl_xor(acc.x, 16, 64); acc.x += __shfl_xor(acc.x, 32, 64);
    acc.y += __shfl_xor(acc.y, 16, 64); acc.y += __shfl_xor(acc.y, 32, 64);
    acc.z += __shfl_xor(acc.z, 16, 64); acc.z += __shfl_xor(acc.z, 32, 64);
    acc.w += __shfl_xor(acc.w, 16, 64); acc.w += __shfl_xor(acc.w, 32, 64);

    if (grp == 0) {
        float inv = 1.f / l;
        float4 bb = ((const float4*)bias)[sub];
        float4 o = make_float4(acc.x*inv + bb.x, acc.y*inv + bb.y,
                               acc.z*inv + bb.z, acc.w*inv + bb.w);
        if constexpr (RELU) {
            o.x = fmaxf(o.x, 0.f); o.y = fmaxf(o.y, 0.f);
            o.z = fmaxf(o.z, 0.f); o.w = fmaxf(o.w, 0.f);
        }
        *(float4*)(OUT + (long)d * 64 + sub * 4) = o;
    }
}

extern "C" void kernel_launch(void* const* d_in, const int* in_sizes, int n_in,
                              void* d_out, int out_size, void* d_ws, size_t ws_size,
                              hipStream_t stream)
{
    const float* x     = (const float*)d_in[0];
    const int*   ei    = (const int*)  d_in[1];
    const float* Wl1   = (const float*)d_in[2];
    const float* bl1   = (const float*)d_in[3];
    const float* Wr1   = (const float*)d_in[4];
    const float* br1   = (const float*)d_in[5];
    const float* att1  = (const float*)d_in[6];
    const float* bias1 = (const float*)d_in[7];
    const float* Wl2   = (const float*)d_in[8];
    const float* bl2   = (const float*)d_in[9];
    const float* Wr2   = (const float*)d_in[10];
    const float* br2   = (const float*)d_in[11];
    const float* att2  = (const float*)d_in[12];
    const float* bias2 = (const float*)d_in[13];

    const int  N  = in_sizes[0] / 128;
    const int  E0 = in_sizes[1] / 2;
    const long ET = (long)E0 + N;
    const int  NB = (N + 1023) / 1024;

    char* w = (char*)d_ws;
    __half* XLh = (__half*)w;                         // N*128 halfs
    __half* XRh = XLh + (size_t)N * 128;              // N*128 halfs
    __half* Cch = XRh + (size_t)N * 128;              // N*128 halfs
    int*    off = (int*)(Cch + (size_t)N * 128);      // N+1
    int*    cnt = off + (N + 1);                      // N
    int*    srcs= cnt + N;                            // ET
    int*    rnk = srcs + ET;                          // ET
    int*    bsum= rnk + ET;                           // NB
    int*    bcar= bsum + NB;                          // NB
    float*  out = (float*)d_out;

    dim3 b256(256);
    const int e4blk = (int)((ET + 1023) / 1024);
    const int ngrid = (N + 3) / 4;
    const int gx    = (N + 127) / 128;

    // ---- CSR build ----
    (void)hipMemsetAsync(cnt, 0, (size_t)N * 4, stream);
    rank_k<<<e4blk, b256, 0, stream>>>(ei, cnt, rnk, E0, N);
    scan1_k<<<NB, b256, 0, stream>>>(cnt, off, bsum, N);
    scan2_k<<<1, 64, 0, stream>>>(bsum, bcar, NB, off + N);
    scan3_k<<<(N + 255) / 256, b256, 0, stream>>>(off, bcar, N);
    scatter_k<<<e4blk, b256, 0, stream>>>(ei, off, rnk, srcs, E0, N);

    // ---- layer 1 ----
    mfma_gemm_k<128, false><<<dim3(gx, 2), b256, 0, stream>>>(
        x, nullptr, Wl1, bl1, Wr1, br1, XLh, XRh, N);
    fused128_k<true><<<ngrid, b256, 0, stream>>>(XLh, XRh, att1, srcs, off, bias1, Cch, N);

    // ---- layer 2 ----
    mfma_gemm_k<64, true><<<dim3(gx, 1), b256, 0, stream>>>(
        nullptr, Cch, Wl2, bl2, Wr2, br2, XLh, XRh, N);
    fused64_k<false><<<ngrid, b256, 0, stream>>>(XLh, XRh, att2, srcs, off, bias2, out, N);
}

// Round 3
// 466.952 us; speedup vs baseline: 1.2129x; 1.0161x over previous
//
#include <hip/hip_runtime.h>
#include <hip/hip_fp16.h>

#define NEG 0.2f

typedef _Float16 f16x8 __attribute__((ext_vector_type(8)));
typedef _Float16 f16x2 __attribute__((ext_vector_type(2)));
typedef float    f32x4 __attribute__((ext_vector_type(4)));

__device__ __forceinline__ float fdot2h(__half2 a, __half2 b, float c) {
    return __builtin_amdgcn_fdot2(__builtin_bit_cast(f16x2, a),
                                  __builtin_bit_cast(f16x2, b), c, false);
}

__device__ __forceinline__ __half2 u2h2(unsigned int u) {
    return __builtin_bit_cast(__half2, u);
}

// packed half2 max via v_pk_max_f16 (ROCm header lacks __hmax2 on this toolchain)
__device__ __forceinline__ __half2 hmax2(__half2 a, __half2 b) {
    unsigned int ua = __builtin_bit_cast(unsigned int, a);
    unsigned int ub = __builtin_bit_cast(unsigned int, b);
    unsigned int ud;
    asm("v_pk_max_f16 %0, %1, %2" : "=v"(ud) : "v"(ua), "v"(ub));
    return __builtin_bit_cast(__half2, ud);
}

// ---- DPP cross-lane add via compiler intrinsic (hazards handled by compiler).
// CTRL: 0xB1 = quad_perm[1,0,3,2] (lane^1), 0x4E = quad_perm[2,3,0,1] (lane^2),
//       0x141 = row_half_mirror (lane^7), 0x140 = row_mirror (lane^15).
template<int CTRL>
__device__ __forceinline__ float dppadd(float x) {
    int xi = __builtin_bit_cast(int, x);
    int yi = __builtin_amdgcn_update_dpp(0, xi, CTRL, 0xf, 0xf, true);
    return x + __builtin_bit_cast(float, yi);
}

// ---------------- MFMA GEMM: Y = half(X[N,128] @ [Wl|Wr] + bias) ----------------
template<int CPW, bool IN_F16>
__global__ __launch_bounds__(256) void mfma_gemm_k(
    const float* __restrict__ Xf, const __half* __restrict__ Xh,
    const float* __restrict__ Wl, const float* __restrict__ bl,
    const float* __restrict__ Wr, const float* __restrict__ br,
    __half* __restrict__ YL, __half* __restrict__ YR, int nrows)
{
    __shared__ _Float16 Xs[128 * 136];
    __shared__ _Float16 Ws[128 * 136];

    const int t    = threadIdx.x;
    const int row0 = blockIdx.x * 128;
    const int c0   = blockIdx.y * 128;

    if constexpr (IN_F16) {
        for (int i = t; i < 128 * 16; i += 256) {
            int r = i >> 4, c = i & 15;
            int gr = row0 + r;
            uint4 v = make_uint4(0u, 0u, 0u, 0u);
            if (gr < nrows) v = ((const uint4*)Xh)[(long)gr * 16 + c];
            *(uint4*)&Xs[r * 136 + c * 8] = v;
        }
    } else {
        for (int i = t; i < 128 * 16; i += 256) {
            int r = i >> 4, c = i & 15;
            int gr = row0 + r;
            float4 a = make_float4(0.f,0.f,0.f,0.f), b4 = make_float4(0.f,0.f,0.f,0.f);
            if (gr < nrows) {
                a  = ((const float4*)Xf)[(long)gr * 32 + c * 2];
                b4 = ((const float4*)Xf)[(long)gr * 32 + c * 2 + 1];
            }
            _Float16 h[8] = {(_Float16)a.x,(_Float16)a.y,(_Float16)a.z,(_Float16)a.w,
                             (_Float16)b4.x,(_Float16)b4.y,(_Float16)b4.z,(_Float16)b4.w};
            *(f16x8*)&Xs[r * 136 + c * 8] = *(f16x8*)h;
        }
    }

    for (int i = t; i < 128 * 128; i += 256) {
        int k = i >> 7, n = i & 127;
        int gc = c0 + n;
        const float* Wp = (gc >= CPW) ? Wr : Wl;
        int lc = gc & (CPW - 1);
        Ws[n * 136 + k] = (_Float16)Wp[(long)k * CPW + lc];
    }
    __syncthreads();

    const int lane  = t & 63;
    const int wv    = t >> 6;
    const int m     = lane & 15;
    const int quad  = lane >> 4;
    const int rbase = wv * 32;

    f16x8 Af[2][4];
    #pragma unroll
    for (int rt = 0; rt < 2; ++rt)
        #pragma unroll
        for (int ks = 0; ks < 4; ++ks)
            Af[rt][ks] = *(const f16x8*)&Xs[(rbase + rt * 16 + m) * 136 + ks * 32 + quad * 8];

    f32x4 acc[2][8];
    #pragma unroll
    for (int rt = 0; rt < 2; ++rt)
        #pragma unroll
        for (int ct = 0; ct < 8; ++ct)
            acc[rt][ct] = (f32x4){0.f, 0.f, 0.f, 0.f};

    #pragma unroll
    for (int ct = 0; ct < 8; ++ct) {
        #pragma unroll
        for (int ks = 0; ks < 4; ++ks) {
            f16x8 Bf = *(const f16x8*)&Ws[(ct * 16 + m) * 136 + ks * 32 + quad * 8];
            acc[0][ct] = __builtin_amdgcn_mfma_f32_16x16x32_f16(Af[0][ks], Bf, acc[0][ct], 0, 0, 0);
            acc[1][ct] = __builtin_amdgcn_mfma_f32_16x16x32_f16(Af[1][ks], Bf, acc[1][ct], 0, 0, 0);
        }
    }

    #pragma unroll
    for (int ct = 0; ct < 8; ++ct) {
        int gc = c0 + ct * 16 + m;
        int which = gc / CPW;
        int lc = gc % CPW;
        _Float16* Y = (_Float16*)(which ? YR : YL);
        float bv = (which ? br : bl)[lc];
        #pragma unroll
        for (int rt = 0; rt < 2; ++rt) {
            int rr = row0 + rbase + rt * 16 + quad * 4;
            #pragma unroll
            for (int g = 0; g < 4; ++g) {
                int r = rr + g;
                if (r < nrows)
                    Y[(long)r * CPW + lc] = (_Float16)(acc[rt][ct][g] + bv);
            }
        }
    }
}

// ---------------- CSR build ----------------
// Pass A: rank of each edge within its dst bucket (atomic+ret, coalesced store).
__global__ __launch_bounds__(256) void rank_k(
    const int* __restrict__ ei, int* __restrict__ cnt, int* __restrict__ rnk,
    int E0, int N)
{
    int e = blockIdx.x * 1024 + threadIdx.x;
    int ET = E0 + N;
    #pragma unroll
    for (int u = 0; u < 4; ++u, e += 256) {
        if (e < ET) {
            int dst = (e < E0) ? ei[E0 + e] : (e - E0);
            rnk[e] = atomicAdd(&cnt[dst], 1);
        }
    }
}

__global__ __launch_bounds__(256) void scan1_k(
    const int* __restrict__ cnt, int* __restrict__ loc, int* __restrict__ bsum, int n)
{
    __shared__ int wsum[4];
    int t = threadIdx.x;
    int i0 = blockIdx.x * 1024 + t * 4;
    int4 v;
    v.x = (i0 + 0 < n) ? cnt[i0 + 0] : 0;
    v.y = (i0 + 1 < n) ? cnt[i0 + 1] : 0;
    v.z = (i0 + 2 < n) ? cnt[i0 + 2] : 0;
    v.w = (i0 + 3 < n) ? cnt[i0 + 3] : 0;
    int tsum = v.x + v.y + v.z + v.w;
    int incl = tsum;
    #pragma unroll
    for (int s = 1; s < 64; s <<= 1) {
        int u = __shfl_up(incl, s, 64);
        if ((t & 63) >= s) incl += u;
    }
    int wid = t >> 6;
    if ((t & 63) == 63) wsum[wid] = incl;
    __syncthreads();
    int woff = 0;
    #pragma unroll
    for (int w = 0; w < 4; ++w) if (w < wid) woff += wsum[w];
    int ex = woff + incl - tsum;
    if (i0 + 0 < n) loc[i0 + 0] = ex;
    if (i0 + 1 < n) loc[i0 + 1] = ex + v.x;
    if (i0 + 2 < n) loc[i0 + 2] = ex + v.x + v.y;
    if (i0 + 3 < n) loc[i0 + 3] = ex + v.x + v.y + v.z;
    if (t == 255) bsum[blockIdx.x] = woff + incl;
}

__global__ void scan2_k(const int* __restrict__ bsum, int* __restrict__ bcarry,
                        int M, int* __restrict__ total_out)
{
    int lane = threadIdx.x;
    int carry = 0;
    for (int base = 0; base < M; base += 64) {
        int i = base + lane;
        int v = (i < M) ? bsum[i] : 0;
        int incl = v;
        #pragma unroll
        for (int s = 1; s < 64; s <<= 1) {
            int u = __shfl_up(incl, s, 64);
            if (lane >= s) incl += u;
        }
        if (i < M) bcarry[i] = carry + incl - v;
        carry += __shfl(incl, 63, 64);
    }
    if (lane == 0) *total_out = carry;
}

__global__ __launch_bounds__(256) void scan3_k(
    int* __restrict__ off, const int* __restrict__ bcarry, int n)
{
    int i = blockIdx.x * 256 + threadIdx.x;
    if (i >= n) return;
    off[i] += bcarry[i >> 10];
}

// Pass C: scatter src into its CSR slot (no atomics, full MLP).
__global__ __launch_bounds__(256) void scatter_k(
    const int* __restrict__ ei, const int* __restrict__ off_,
    const int* __restrict__ rnk, int* __restrict__ srcs, int E0, int N)
{
    int e = blockIdx.x * 1024 + threadIdx.x;
    int ET = E0 + N;
    #pragma unroll
    for (int u = 0; u < 4; ++u, e += 256) {
        if (e < ET) {
            int src = (e < E0) ? ei[e]      : (e - E0);
            int dst = (e < E0) ? ei[E0 + e] : (e - E0);
            srcs[off_[dst] + rnk[e]] = src;
        }
    }
}

// ---------------- fused score + softmax + aggregation, per dst node ----------------
// Layer 1: H=4, C=32. One wave per dst node; 4 edge-slots x 16 lanes;
// each lane owns 8 consecutive feats (head = sub>>2). Score reduce = 2 DPP adds.
// Depth-2 software pipeline: XL row for iter i+1 and srcs for iter i+2 are
// issued before computing on iter i's row.
template<bool RELU>
__global__ __launch_bounds__(256) void fused128_k(
    const __half* __restrict__ XL, const __half* __restrict__ XR,
    const float* __restrict__ ATT, const int* __restrict__ srcs,
    const int* __restrict__ off, const float* __restrict__ bias,
    __half* __restrict__ OUT, int N)
{
    int d = blockIdx.x * 4 + (threadIdx.x >> 6);
    if (d >= N) return;
    const int lane = threadIdx.x & 63;
    const int sub  = lane & 15;   // feats 8*sub .. 8*sub+7 (all in head sub>>2)
    const int grp  = lane >> 4;   // edge slot 0..3
    int a = off[d], b = off[d + 1];

    uint4 ur = *(const uint4*)(XR + (long)d * 128 + sub * 8);
    __half2 xr[4] = { u2h2(ur.x), u2h2(ur.y), u2h2(ur.z), u2h2(ur.w) };
    float4 at0f = ((const float4*)ATT)[sub * 2];
    float4 at1f = ((const float4*)ATT)[sub * 2 + 1];
    __half2 at[4] = { __floats2half2_rn(at0f.x, at0f.y), __floats2half2_rn(at0f.z, at0f.w),
                      __floats2half2_rn(at1f.x, at1f.y), __floats2half2_rn(at1f.z, at1f.w) };
    const __half2 neg2 = __float2half2_rn(NEG);

    float l = 0.f;
    float accv[8] = {0.f,0.f,0.f,0.f,0.f,0.f,0.f,0.f};

    const uint4* XL4 = (const uint4*)XL;

    // pipeline prologue: row for iter 0, srcs for iter 1
    int e0g = a + grp;
    int sc = srcs[e0g < b ? e0g : b - 1];
    uint4 ux = XL4[(long)sc * 16 + sub];
    int e1g = e0g + 4;
    int sn = srcs[e1g < b ? e1g : b - 1];

    for (int e0 = a; e0 < b; e0 += 4) {
        // issue next iter's row + iter-after-next's srcs
        uint4 uxn = XL4[(long)sn * 16 + sub];
        int e2g = e0 + 8 + grp;
        int sn2 = srcs[e2g < b ? e2g : b - 1];

        bool valid = (e0 + grp) < b;
        __half2 x0 = u2h2(ux.x), x1 = u2h2(ux.y), x2 = u2h2(ux.z), x3 = u2h2(ux.w);

        __half2 s0 = __hadd2(x0, xr[0]);
        __half2 s1 = __hadd2(x1, xr[1]);
        __half2 s2 = __hadd2(x2, xr[2]);
        __half2 s3 = __hadd2(x3, xr[3]);
        __half2 q0 = hmax2(s0, __hmul2(s0, neg2));
        __half2 q1 = hmax2(s1, __hmul2(s1, neg2));
        __half2 q2 = hmax2(s2, __hmul2(s2, neg2));
        __half2 q3 = hmax2(s3, __hmul2(s3, neg2));
        float p = fdot2h(q0, at[0], 0.f);
        p = fdot2h(q1, at[1], p);
        p = fdot2h(q2, at[2], p);
        p = fdot2h(q3, at[3], p);
        // reduce over 4-lane head group (bit-exact vs shfl_xor 1,2)
        p = dppadd<0xB1>(p);   // + lane^1
        p = dppadd<0x4E>(p);   // + lane^2
        float ex = valid ? __expf(p) : 0.f;
        l += ex;
        float2 f0 = __half22float2(x0), f1 = __half22float2(x1);
        float2 f2 = __half22float2(x2), f3 = __half22float2(x3);
        accv[0] += ex * f0.x; accv[1] += ex * f0.y;
        accv[2] += ex * f1.x; accv[3] += ex * f1.y;
        accv[4] += ex * f2.x; accv[5] += ex * f2.y;
        accv[6] += ex * f3.x; accv[7] += ex * f3.y;

        ux = uxn; sn = sn2;
    }

    // combine the 4 edge slots (lane bits 4,5)
    l += __shfl_xor(l, 16, 64);
    l += __shfl_xor(l, 32, 64);
    #pragma unroll
    for (int j = 0; j < 8; ++j) {
        accv[j] += __shfl_xor(accv[j], 16, 64);
        accv[j] += __shfl_xor(accv[j], 32, 64);
    }

    if (grp == 0) {
        float inv = 1.f / l;
        float4 b0 = ((const float4*)bias)[sub * 2];
        float4 b1 = ((const float4*)bias)[sub * 2 + 1];
        float o[8] = { accv[0]*inv + b0.x, accv[1]*inv + b0.y,
                       accv[2]*inv + b0.z, accv[3]*inv + b0.w,
                       accv[4]*inv + b1.x, accv[5]*inv + b1.y,
                       accv[6]*inv + b1.z, accv[7]*inv + b1.w };
        if constexpr (RELU) {
            #pragma unroll
            for (int j = 0; j < 8; ++j) o[j] = fmaxf(o[j], 0.f);
        }
        uint4 uo;
        uo.x = __builtin_bit_cast(unsigned int, __floats2half2_rn(o[0], o[1]));
        uo.y = __builtin_bit_cast(unsigned int, __floats2half2_rn(o[2], o[3]));
        uo.z = __builtin_bit_cast(unsigned int, __floats2half2_rn(o[4], o[5]));
        uo.w = __builtin_bit_cast(unsigned int, __floats2half2_rn(o[6], o[7]));
        *(uint4*)(OUT + (long)d * 128 + sub * 8) = uo;
    }
}

// Layer 2: H=1, C=64. One wave per dst node; 4 edge-slots x 16 lanes;
// each lane owns 4 consecutive feats. Score reduce = 4 DPP adds over 16 lanes.
// Same depth-2 pipeline as fused128_k.
template<bool RELU>
__global__ __launch_bounds__(256) void fused64_k(
    const __half* __restrict__ XL, const __half* __restrict__ XR,
    const float* __restrict__ ATT, const int* __restrict__ srcs,
    const int* __restrict__ off, const float* __restrict__ bias,
    float* __restrict__ OUT, int N)
{
    int d = blockIdx.x * 4 + (threadIdx.x >> 6);
    if (d >= N) return;
    const int lane = threadIdx.x & 63;
    const int sub  = lane & 15;   // feats 4*sub .. 4*sub+3
    const int grp  = lane >> 4;   // edge slot 0..3
    int a = off[d], b = off[d + 1];

    uint2 ur = *(const uint2*)(XR + (long)d * 64 + sub * 4);
    __half2 xr0 = u2h2(ur.x), xr1 = u2h2(ur.y);
    float4 atf = ((const float4*)ATT)[sub];
    __half2 at0 = __floats2half2_rn(atf.x, atf.y);
    __half2 at1 = __floats2half2_rn(atf.z, atf.w);
    const __half2 neg2 = __float2half2_rn(NEG);

    float l = 0.f;
    float4 acc = make_float4(0.f, 0.f, 0.f, 0.f);

    const uint2* XL2 = (const uint2*)XL;

    int e0g = a + grp;
    int sc = srcs[e0g < b ? e0g : b - 1];
    uint2 ux = XL2[(long)sc * 16 + sub];
    int e1g = e0g + 4;
    int sn = srcs[e1g < b ? e1g : b - 1];

    for (int e0 = a; e0 < b; e0 += 4) {
        uint2 uxn = XL2[(long)sn * 16 + sub];
        int e2g = e0 + 8 + grp;
        int sn2 = srcs[e2g < b ? e2g : b - 1];

        bool valid = (e0 + grp) < b;
        __half2 x0 = u2h2(ux.x), x1 = u2h2(ux.y);

        __half2 s0 = __hadd2(x0, xr0);
        __half2 s1 = __hadd2(x1, xr1);
        __half2 q0 = hmax2(s0, __hmul2(s0, neg2));
        __half2 q1 = hmax2(s1, __hmul2(s1, neg2));
        float p = fdot2h(q1, at1, fdot2h(q0, at0, 0.f));
        // reduce over the 16-lane group (bit-exact vs shfl_xor 1,2,4,8)
        p = dppadd<0xB1>(p);    // + lane^1
        p = dppadd<0x4E>(p);    // + lane^2
        p = dppadd<0x141>(p);   // row_half_mirror == xor4 at this stage
        p = dppadd<0x140>(p);   // row_mirror == xor8 at this stage
        float ex = valid ? __expf(p) : 0.f;
        float2 f0 = __half22float2(x0), f1 = __half22float2(x1);
        l += ex;
        acc.x += ex * f0.x; acc.y += ex * f0.y;
        acc.z += ex * f1.x; acc.w += ex * f1.y;

        ux = uxn; sn = sn2;
    }

    // combine the 4 edge slots
    l += __shfl_xor(l, 16, 64);
    l += __shfl_xor(l, 32, 64);
    acc.x += __shfl_xor(acc.x, 16, 64); acc.x += __shfl_xor(acc.x, 32, 64);
    acc.y += __shfl_xor(acc.y, 16, 64); acc.y += __shfl_xor(acc.y, 32, 64);
    acc.z += __shfl_xor(acc.z, 16, 64); acc.z += __shfl_xor(acc.z, 32, 64);
    acc.w += __shfl_xor(acc.w, 16, 64); acc.w += __shfl_xor(acc.w, 32, 64);

    if (grp == 0) {
        float inv = 1.f / l;
        float4 bb = ((const float4*)bias)[sub];
        float4 o = make_float4(acc.x*inv + bb.x, acc.y*inv + bb.y,
                               acc.z*inv + bb.z, acc.w*inv + bb.w);
        if constexpr (RELU) {
            o.x = fmaxf(o.x, 0.f); o.y = fmaxf(o.y, 0.f);
            o.z = fmaxf(o.z, 0.f); o.w = fmaxf(o.w, 0.f);
        }
        *(float4*)(OUT + (long)d * 64 + sub * 4) = o;
    }
}

extern "C" void kernel_launch(void* const* d_in, const int* in_sizes, int n_in,
                              void* d_out, int out_size, void* d_ws, size_t ws_size,
                              hipStream_t stream)
{
    const float* x     = (const float*)d_in[0];
    const int*   ei    = (const int*)  d_in[1];
    const float* Wl1   = (const float*)d_in[2];
    const float* bl1   = (const float*)d_in[3];
    const float* Wr1   = (const float*)d_in[4];
    const float* br1   = (const float*)d_in[5];
    const float* att1  = (const float*)d_in[6];
    const float* bias1 = (const float*)d_in[7];
    const float* Wl2   = (const float*)d_in[8];
    const float* bl2   = (const float*)d_in[9];
    const float* Wr2   = (const float*)d_in[10];
    const float* br2   = (const float*)d_in[11];
    const float* att2  = (const float*)d_in[12];
    const float* bias2 = (const float*)d_in[13];

    const int  N  = in_sizes[0] / 128;
    const int  E0 = in_sizes[1] / 2;
    const long ET = (long)E0 + N;
    const int  NB = (N + 1023) / 1024;

    char* w = (char*)d_ws;
    __half* XLh = (__half*)w;                         // N*128 halfs
    __half* XRh = XLh + (size_t)N * 128;              // N*128 halfs
    __half* Cch = XRh + (size_t)N * 128;              // N*128 halfs
    int*    off = (int*)(Cch + (size_t)N * 128);      // N+1
    int*    cnt = off + (N + 1);                      // N
    int*    srcs= cnt + N;                            // ET
    int*    rnk = srcs + ET;                          // ET
    int*    bsum= rnk + ET;                           // NB
    int*    bcar= bsum + NB;                          // NB
    float*  out = (float*)d_out;

    dim3 b256(256);
    const int e4blk = (int)((ET + 1023) / 1024);
    const int ngrid = (N + 3) / 4;
    const int gx    = (N + 127) / 128;

    // ---- CSR build ----
    (void)hipMemsetAsync(cnt, 0, (size_t)N * 4, stream);
    rank_k<<<e4blk, b256, 0, stream>>>(ei, cnt, rnk, E0, N);
    scan1_k<<<NB, b256, 0, stream>>>(cnt, off, bsum, N);
    scan2_k<<<1, 64, 0, stream>>>(bsum, bcar, NB, off + N);
    scan3_k<<<(N + 255) / 256, b256, 0, stream>>>(off, bcar, N);
    scatter_k<<<e4blk, b256, 0, stream>>>(ei, off, rnk, srcs, E0, N);

    // ---- layer 1 ----
    mfma_gemm_k<128, false><<<dim3(gx, 2), b256, 0, stream>>>(
        x, nullptr, Wl1, bl1, Wr1, br1, XLh, XRh, N);
    fused128_k<true><<<ngrid, b256, 0, stream>>>(XLh, XRh, att1, srcs, off, bias1, Cch, N);

    // ---- layer 2 ----
    mfma_gemm_k<64, true><<<dim3(gx, 1), b256, 0, stream>>>(
        nullptr, Cch, Wl2, bl2, Wr2, br2, XLh, XRh, N);
    fused64_k<false><<<ngrid, b256, 0, stream>>>(XLh, XRh, att2, srcs, off, bias2, out, N);
}

// Round 4
// 465.728 us; speedup vs baseline: 1.2161x; 1.0026x over previous
//
#include <hip/hip_runtime.h>
#include <hip/hip_fp16.h>

#define NEG 0.2f

typedef _Float16 f16x8 __attribute__((ext_vector_type(8)));
typedef _Float16 f16x2 __attribute__((ext_vector_type(2)));
typedef float    f32x4 __attribute__((ext_vector_type(4)));

__device__ __forceinline__ float fdot2h(__half2 a, __half2 b, float c) {
    return __builtin_amdgcn_fdot2(__builtin_bit_cast(f16x2, a),
                                  __builtin_bit_cast(f16x2, b), c, false);
}

__device__ __forceinline__ __half2 u2h2(unsigned int u) {
    return __builtin_bit_cast(__half2, u);
}

// packed half2 max via v_pk_max_f16 (ROCm header lacks __hmax2 on this toolchain)
__device__ __forceinline__ __half2 hmax2(__half2 a, __half2 b) {
    unsigned int ua = __builtin_bit_cast(unsigned int, a);
    unsigned int ub = __builtin_bit_cast(unsigned int, b);
    unsigned int ud;
    asm("v_pk_max_f16 %0, %1, %2" : "=v"(ud) : "v"(ua), "v"(ub));
    return __builtin_bit_cast(__half2, ud);
}

// ---- DPP cross-lane add via compiler intrinsic (hazards handled by compiler).
// CTRL: 0xB1 = quad_perm[1,0,3,2] (lane^1), 0x4E = quad_perm[2,3,0,1] (lane^2),
//       0x141 = row_half_mirror (==xor4 after the xor1,xor2 stages).
template<int CTRL>
__device__ __forceinline__ float dppadd(float x) {
    int xi = __builtin_bit_cast(int, x);
    int yi = __builtin_amdgcn_update_dpp(0, xi, CTRL, 0xf, 0xf, true);
    return x + __builtin_bit_cast(float, yi);
}

// ---------------- MFMA GEMM: Y = half(X[N,128] @ [Wl|Wr] + bias) ----------------
template<int CPW, bool IN_F16>
__global__ __launch_bounds__(256) void mfma_gemm_k(
    const float* __restrict__ Xf, const __half* __restrict__ Xh,
    const float* __restrict__ Wl, const float* __restrict__ bl,
    const float* __restrict__ Wr, const float* __restrict__ br,
    __half* __restrict__ YL, __half* __restrict__ YR, int nrows)
{
    __shared__ _Float16 Xs[128 * 136];
    __shared__ _Float16 Ws[128 * 136];

    const int t    = threadIdx.x;
    const int row0 = blockIdx.x * 128;
    const int c0   = blockIdx.y * 128;

    if constexpr (IN_F16) {
        for (int i = t; i < 128 * 16; i += 256) {
            int r = i >> 4, c = i & 15;
            int gr = row0 + r;
            uint4 v = make_uint4(0u, 0u, 0u, 0u);
            if (gr < nrows) v = ((const uint4*)Xh)[(long)gr * 16 + c];
            *(uint4*)&Xs[r * 136 + c * 8] = v;
        }
    } else {
        for (int i = t; i < 128 * 16; i += 256) {
            int r = i >> 4, c = i & 15;
            int gr = row0 + r;
            float4 a = make_float4(0.f,0.f,0.f,0.f), b4 = make_float4(0.f,0.f,0.f,0.f);
            if (gr < nrows) {
                a  = ((const float4*)Xf)[(long)gr * 32 + c * 2];
                b4 = ((const float4*)Xf)[(long)gr * 32 + c * 2 + 1];
            }
            _Float16 h[8] = {(_Float16)a.x,(_Float16)a.y,(_Float16)a.z,(_Float16)a.w,
                             (_Float16)b4.x,(_Float16)b4.y,(_Float16)b4.z,(_Float16)b4.w};
            *(f16x8*)&Xs[r * 136 + c * 8] = *(f16x8*)h;
        }
    }

    for (int i = t; i < 128 * 128; i += 256) {
        int k = i >> 7, n = i & 127;
        int gc = c0 + n;
        const float* Wp = (gc >= CPW) ? Wr : Wl;
        int lc = gc & (CPW - 1);
        Ws[n * 136 + k] = (_Float16)Wp[(long)k * CPW + lc];
    }
    __syncthreads();

    const int lane  = t & 63;
    const int wv    = t >> 6;
    const int m     = lane & 15;
    const int quad  = lane >> 4;
    const int rbase = wv * 32;

    f16x8 Af[2][4];
    #pragma unroll
    for (int rt = 0; rt < 2; ++rt)
        #pragma unroll
        for (int ks = 0; ks < 4; ++ks)
            Af[rt][ks] = *(const f16x8*)&Xs[(rbase + rt * 16 + m) * 136 + ks * 32 + quad * 8];

    f32x4 acc[2][8];
    #pragma unroll
    for (int rt = 0; rt < 2; ++rt)
        #pragma unroll
        for (int ct = 0; ct < 8; ++ct)
            acc[rt][ct] = (f32x4){0.f, 0.f, 0.f, 0.f};

    #pragma unroll
    for (int ct = 0; ct < 8; ++ct) {
        #pragma unroll
        for (int ks = 0; ks < 4; ++ks) {
            f16x8 Bf = *(const f16x8*)&Ws[(ct * 16 + m) * 136 + ks * 32 + quad * 8];
            acc[0][ct] = __builtin_amdgcn_mfma_f32_16x16x32_f16(Af[0][ks], Bf, acc[0][ct], 0, 0, 0);
            acc[1][ct] = __builtin_amdgcn_mfma_f32_16x16x32_f16(Af[1][ks], Bf, acc[1][ct], 0, 0, 0);
        }
    }

    #pragma unroll
    for (int ct = 0; ct < 8; ++ct) {
        int gc = c0 + ct * 16 + m;
        int which = gc / CPW;
        int lc = gc % CPW;
        _Float16* Y = (_Float16*)(which ? YR : YL);
        float bv = (which ? br : bl)[lc];
        #pragma unroll
        for (int rt = 0; rt < 2; ++rt) {
            int rr = row0 + rbase + rt * 16 + quad * 4;
            #pragma unroll
            for (int g = 0; g < 4; ++g) {
                int r = rr + g;
                if (r < nrows)
                    Y[(long)r * CPW + lc] = (_Float16)(acc[rt][ct][g] + bv);
            }
        }
    }
}

// ---------------- CSR build ----------------
// Pass A: rank of each edge within its dst bucket (atomic+ret, coalesced store).
__global__ __launch_bounds__(256) void rank_k(
    const int* __restrict__ ei, int* __restrict__ cnt, int* __restrict__ rnk,
    int E0, int N)
{
    int e = blockIdx.x * 1024 + threadIdx.x;
    int ET = E0 + N;
    #pragma unroll
    for (int u = 0; u < 4; ++u, e += 256) {
        if (e < ET) {
            int dst = (e < E0) ? ei[E0 + e] : (e - E0);
            rnk[e] = atomicAdd(&cnt[dst], 1);
        }
    }
}

__global__ __launch_bounds__(256) void scan1_k(
    const int* __restrict__ cnt, int* __restrict__ loc, int* __restrict__ bsum, int n)
{
    __shared__ int wsum[4];
    int t = threadIdx.x;
    int i0 = blockIdx.x * 1024 + t * 4;
    int4 v;
    v.x = (i0 + 0 < n) ? cnt[i0 + 0] : 0;
    v.y = (i0 + 1 < n) ? cnt[i0 + 1] : 0;
    v.z = (i0 + 2 < n) ? cnt[i0 + 2] : 0;
    v.w = (i0 + 3 < n) ? cnt[i0 + 3] : 0;
    int tsum = v.x + v.y + v.z + v.w;
    int incl = tsum;
    #pragma unroll
    for (int s = 1; s < 64; s <<= 1) {
        int u = __shfl_up(incl, s, 64);
        if ((t & 63) >= s) incl += u;
    }
    int wid = t >> 6;
    if ((t & 63) == 63) wsum[wid] = incl;
    __syncthreads();
    int woff = 0;
    #pragma unroll
    for (int w = 0; w < 4; ++w) if (w < wid) woff += wsum[w];
    int ex = woff + incl - tsum;
    if (i0 + 0 < n) loc[i0 + 0] = ex;
    if (i0 + 1 < n) loc[i0 + 1] = ex + v.x;
    if (i0 + 2 < n) loc[i0 + 2] = ex + v.x + v.y;
    if (i0 + 3 < n) loc[i0 + 3] = ex + v.x + v.y + v.z;
    if (t == 255) bsum[blockIdx.x] = woff + incl;
}

__global__ void scan2_k(const int* __restrict__ bsum, int* __restrict__ bcarry,
                        int M, int* __restrict__ total_out)
{
    int lane = threadIdx.x;
    int carry = 0;
    for (int base = 0; base < M; base += 64) {
        int i = base + lane;
        int v = (i < M) ? bsum[i] : 0;
        int incl = v;
        #pragma unroll
        for (int s = 1; s < 64; s <<= 1) {
            int u = __shfl_up(incl, s, 64);
            if (lane >= s) incl += u;
        }
        if (i < M) bcarry[i] = carry + incl - v;
        carry += __shfl(incl, 63, 64);
    }
    if (lane == 0) *total_out = carry;
}

__global__ __launch_bounds__(256) void scan3_k(
    int* __restrict__ off, const int* __restrict__ bcarry, int n)
{
    int i = blockIdx.x * 256 + threadIdx.x;
    if (i >= n) return;
    off[i] += bcarry[i >> 10];
}

// Pass C: scatter src into its CSR slot (no atomics, full MLP).
__global__ __launch_bounds__(256) void scatter_k(
    const int* __restrict__ ei, const int* __restrict__ off_,
    const int* __restrict__ rnk, int* __restrict__ srcs, int E0, int N)
{
    int e = blockIdx.x * 1024 + threadIdx.x;
    int ET = E0 + N;
    #pragma unroll
    for (int u = 0; u < 4; ++u, e += 256) {
        if (e < ET) {
            int src = (e < E0) ? ei[e]      : (e - E0);
            int dst = (e < E0) ? ei[E0 + e] : (e - E0);
            srcs[off_[dst] + rnk[e]] = src;
        }
    }
}

// ---------------- fused score + softmax + aggregation, per dst node ----------------
// Layer 1: H=4, C=32. One node per 16-lane GROUP (16 nodes/block, 4/wave);
// each lane owns 8 consecutive feats (head = sub>>2). Loop = full degree
// (amortizes the off->srcs->row serial prologue over ~17 iters, no cross-slot
// epilogue). Depth-2 row prefetch: row for e+2 and srcs for e+3 issued per iter.
template<bool RELU>
__global__ __launch_bounds__(256) void fused128_k(
    const __half* __restrict__ XL, const __half* __restrict__ XR,
    const float* __restrict__ ATT, const int* __restrict__ srcs,
    const int* __restrict__ off, const float* __restrict__ bias,
    __half* __restrict__ OUT, int N)
{
    const int t   = threadIdx.x;
    const int d   = blockIdx.x * 16 + (t >> 4);   // node for this 16-lane group
    const int sub = t & 15;                       // feats 8*sub..8*sub+7
    const bool nv = d < N;

    int a = 0, b = 0;
    if (nv) { a = off[d]; b = off[d + 1]; }

    __half2 xr[4] = { u2h2(0), u2h2(0), u2h2(0), u2h2(0) };
    if (nv) {
        uint4 ur = *(const uint4*)(XR + (long)d * 128 + sub * 8);
        xr[0] = u2h2(ur.x); xr[1] = u2h2(ur.y); xr[2] = u2h2(ur.z); xr[3] = u2h2(ur.w);
    }
    float4 at0f = ((const float4*)ATT)[sub * 2];
    float4 at1f = ((const float4*)ATT)[sub * 2 + 1];
    __half2 at[4] = { __floats2half2_rn(at0f.x, at0f.y), __floats2half2_rn(at0f.z, at0f.w),
                      __floats2half2_rn(at1f.x, at1f.y), __floats2half2_rn(at1f.z, at1f.w) };
    const __half2 neg2 = __float2half2_rn(NEG);

    float l = 0.f;
    float accv[8] = {0.f,0.f,0.f,0.f,0.f,0.f,0.f,0.f};

    const uint4* XL4 = (const uint4*)XL;

    if (b > a) {   // degree >= 1 always for valid nodes (self-loops)
        const int bm1 = b - 1;
        int sA = srcs[a];
        uint4 r0 = XL4[(long)sA * 16 + sub];
        int i1 = (a + 1 < bm1) ? a + 1 : bm1;
        int sB = srcs[i1];
        uint4 r1 = XL4[(long)sB * 16 + sub];
        int i2 = (a + 2 < bm1) ? a + 2 : bm1;
        int s2 = srcs[i2];

        for (int e = a; e < b; ++e) {
            uint4 r2 = XL4[(long)s2 * 16 + sub];            // row for e+2
            int i3 = (e + 3 < bm1) ? e + 3 : bm1;
            int s3 = srcs[i3];                               // srcs for e+3

            __half2 x0 = u2h2(r0.x), x1 = u2h2(r0.y), x2 = u2h2(r0.z), x3 = u2h2(r0.w);
            __half2 s0h = __hadd2(x0, xr[0]);
            __half2 s1h = __hadd2(x1, xr[1]);
            __half2 s2h = __hadd2(x2, xr[2]);
            __half2 s3h = __hadd2(x3, xr[3]);
            __half2 q0 = hmax2(s0h, __hmul2(s0h, neg2));
            __half2 q1 = hmax2(s1h, __hmul2(s1h, neg2));
            __half2 q2 = hmax2(s2h, __hmul2(s2h, neg2));
            __half2 q3 = hmax2(s3h, __hmul2(s3h, neg2));
            float p = fdot2h(q0, at[0], 0.f);
            p = fdot2h(q1, at[1], p);
            p = fdot2h(q2, at[2], p);
            p = fdot2h(q3, at[3], p);
            // reduce over the 4-lane head group
            p = dppadd<0xB1>(p);   // + lane^1
            p = dppadd<0x4E>(p);   // + lane^2
            float ex = __expf(p);
            l += ex;
            float2 f0 = __half22float2(x0), f1 = __half22float2(x1);
            float2 f2 = __half22float2(x2), f3 = __half22float2(x3);
            accv[0] += ex * f0.x; accv[1] += ex * f0.y;
            accv[2] += ex * f1.x; accv[3] += ex * f1.y;
            accv[4] += ex * f2.x; accv[5] += ex * f2.y;
            accv[6] += ex * f3.x; accv[7] += ex * f3.y;

            r0 = r1; r1 = r2; s2 = s3;
        }
    }

    if (nv) {
        float inv = 1.f / l;
        float4 b0 = ((const float4*)bias)[sub * 2];
        float4 b1 = ((const float4*)bias)[sub * 2 + 1];
        float o[8] = { accv[0]*inv + b0.x, accv[1]*inv + b0.y,
                       accv[2]*inv + b0.z, accv[3]*inv + b0.w,
                       accv[4]*inv + b1.x, accv[5]*inv + b1.y,
                       accv[6]*inv + b1.z, accv[7]*inv + b1.w };
        if constexpr (RELU) {
            #pragma unroll
            for (int j = 0; j < 8; ++j) o[j] = fmaxf(o[j], 0.f);
        }
        uint4 uo;
        uo.x = __builtin_bit_cast(unsigned int, __floats2half2_rn(o[0], o[1]));
        uo.y = __builtin_bit_cast(unsigned int, __floats2half2_rn(o[2], o[3]));
        uo.z = __builtin_bit_cast(unsigned int, __floats2half2_rn(o[4], o[5]));
        uo.w = __builtin_bit_cast(unsigned int, __floats2half2_rn(o[6], o[7]));
        *(uint4*)(OUT + (long)d * 128 + sub * 8) = uo;
    }
}

// Layer 2: H=1, C=64. One node per 8-lane GROUP (32 nodes/block, 8/wave);
// each lane owns 8 consecutive feats. Score reduce = 3 DPP adds over 8 lanes.
// Same depth-2 prefetch structure as fused128_k.
template<bool RELU>
__global__ __launch_bounds__(256) void fused64_k(
    const __half* __restrict__ XL, const __half* __restrict__ XR,
    const float* __restrict__ ATT, const int* __restrict__ srcs,
    const int* __restrict__ off, const float* __restrict__ bias,
    float* __restrict__ OUT, int N)
{
    const int t   = threadIdx.x;
    const int d   = blockIdx.x * 32 + (t >> 3);   // node for this 8-lane group
    const int sub = t & 7;                        // feats 8*sub..8*sub+7
    const bool nv = d < N;

    int a = 0, b = 0;
    if (nv) { a = off[d]; b = off[d + 1]; }

    __half2 xr[4] = { u2h2(0), u2h2(0), u2h2(0), u2h2(0) };
    if (nv) {
        uint4 ur = *(const uint4*)(XR + (long)d * 64 + sub * 8);
        xr[0] = u2h2(ur.x); xr[1] = u2h2(ur.y); xr[2] = u2h2(ur.z); xr[3] = u2h2(ur.w);
    }
    float4 at0f = ((const float4*)ATT)[sub * 2];
    float4 at1f = ((const float4*)ATT)[sub * 2 + 1];
    __half2 at[4] = { __floats2half2_rn(at0f.x, at0f.y), __floats2half2_rn(at0f.z, at0f.w),
                      __floats2half2_rn(at1f.x, at1f.y), __floats2half2_rn(at1f.z, at1f.w) };
    const __half2 neg2 = __float2half2_rn(NEG);

    float l = 0.f;
    float accv[8] = {0.f,0.f,0.f,0.f,0.f,0.f,0.f,0.f};

    const uint4* XL4 = (const uint4*)XL;

    if (b > a) {
        const int bm1 = b - 1;
        int sA = srcs[a];
        uint4 r0 = XL4[(long)sA * 8 + sub];
        int i1 = (a + 1 < bm1) ? a + 1 : bm1;
        int sB = srcs[i1];
        uint4 r1 = XL4[(long)sB * 8 + sub];
        int i2 = (a + 2 < bm1) ? a + 2 : bm1;
        int s2 = srcs[i2];

        for (int e = a; e < b; ++e) {
            uint4 r2 = XL4[(long)s2 * 8 + sub];
            int i3 = (e + 3 < bm1) ? e + 3 : bm1;
            int s3 = srcs[i3];

            __half2 x0 = u2h2(r0.x), x1 = u2h2(r0.y), x2 = u2h2(r0.z), x3 = u2h2(r0.w);
            __half2 s0h = __hadd2(x0, xr[0]);
            __half2 s1h = __hadd2(x1, xr[1]);
            __half2 s2h = __hadd2(x2, xr[2]);
            __half2 s3h = __hadd2(x3, xr[3]);
            __half2 q0 = hmax2(s0h, __hmul2(s0h, neg2));
            __half2 q1 = hmax2(s1h, __hmul2(s1h, neg2));
            __half2 q2 = hmax2(s2h, __hmul2(s2h, neg2));
            __half2 q3 = hmax2(s3h, __hmul2(s3h, neg2));
            float p = fdot2h(q0, at[0], 0.f);
            p = fdot2h(q1, at[1], p);
            p = fdot2h(q2, at[2], p);
            p = fdot2h(q3, at[3], p);
            // reduce over the 8-lane group
            p = dppadd<0xB1>(p);    // + lane^1
            p = dppadd<0x4E>(p);    // + lane^2
            p = dppadd<0x141>(p);   // row_half_mirror == xor4 at this stage
            float ex = __expf(p);
            l += ex;
            float2 f0 = __half22float2(x0), f1 = __half22float2(x1);
            float2 f2 = __half22float2(x2), f3 = __half22float2(x3);
            accv[0] += ex * f0.x; accv[1] += ex * f0.y;
            accv[2] += ex * f1.x; accv[3] += ex * f1.y;
            accv[4] += ex * f2.x; accv[5] += ex * f2.y;
            accv[6] += ex * f3.x; accv[7] += ex * f3.y;

            r0 = r1; r1 = r2; s2 = s3;
        }
    }

    if (nv) {
        float inv = 1.f / l;
        float4 b0 = ((const float4*)bias)[sub * 2];
        float4 b1 = ((const float4*)bias)[sub * 2 + 1];
        float4 o0 = make_float4(accv[0]*inv + b0.x, accv[1]*inv + b0.y,
                                accv[2]*inv + b0.z, accv[3]*inv + b0.w);
        float4 o1 = make_float4(accv[4]*inv + b1.x, accv[5]*inv + b1.y,
                                accv[6]*inv + b1.z, accv[7]*inv + b1.w);
        if constexpr (RELU) {
            o0.x = fmaxf(o0.x, 0.f); o0.y = fmaxf(o0.y, 0.f);
            o0.z = fmaxf(o0.z, 0.f); o0.w = fmaxf(o0.w, 0.f);
            o1.x = fmaxf(o1.x, 0.f); o1.y = fmaxf(o1.y, 0.f);
            o1.z = fmaxf(o1.z, 0.f); o1.w = fmaxf(o1.w, 0.f);
        }
        *(float4*)(OUT + (long)d * 64 + sub * 8)     = o0;
        *(float4*)(OUT + (long)d * 64 + sub * 8 + 4) = o1;
    }
}

extern "C" void kernel_launch(void* const* d_in, const int* in_sizes, int n_in,
                              void* d_out, int out_size, void* d_ws, size_t ws_size,
                              hipStream_t stream)
{
    const float* x     = (const float*)d_in[0];
    const int*   ei    = (const int*)  d_in[1];
    const float* Wl1   = (const float*)d_in[2];
    const float* bl1   = (const float*)d_in[3];
    const float* Wr1   = (const float*)d_in[4];
    const float* br1   = (const float*)d_in[5];
    const float* att1  = (const float*)d_in[6];
    const float* bias1 = (const float*)d_in[7];
    const float* Wl2   = (const float*)d_in[8];
    const float* bl2   = (const float*)d_in[9];
    const float* Wr2   = (const float*)d_in[10];
    const float* br2   = (const float*)d_in[11];
    const float* att2  = (const float*)d_in[12];
    const float* bias2 = (const float*)d_in[13];

    const int  N  = in_sizes[0] / 128;
    const int  E0 = in_sizes[1] / 2;
    const long ET = (long)E0 + N;
    const int  NB = (N + 1023) / 1024;

    char* w = (char*)d_ws;
    __half* XLh = (__half*)w;                         // N*128 halfs
    __half* XRh = XLh + (size_t)N * 128;              // N*128 halfs
    __half* Cch = XRh + (size_t)N * 128;              // N*128 halfs
    int*    off = (int*)(Cch + (size_t)N * 128);      // N+1
    int*    cnt = off + (N + 1);                      // N
    int*    srcs= cnt + N;                            // ET
    int*    rnk = srcs + ET;                          // ET
    int*    bsum= rnk + ET;                           // NB
    int*    bcar= bsum + NB;                          // NB
    float*  out = (float*)d_out;

    dim3 b256(256);
    const int e4blk = (int)((ET + 1023) / 1024);
    const int gx    = (N + 127) / 128;

    // ---- CSR build ----
    (void)hipMemsetAsync(cnt, 0, (size_t)N * 4, stream);
    rank_k<<<e4blk, b256, 0, stream>>>(ei, cnt, rnk, E0, N);
    scan1_k<<<NB, b256, 0, stream>>>(cnt, off, bsum, N);
    scan2_k<<<1, 64, 0, stream>>>(bsum, bcar, NB, off + N);
    scan3_k<<<(N + 255) / 256, b256, 0, stream>>>(off, bcar, N);
    scatter_k<<<e4blk, b256, 0, stream>>>(ei, off, rnk, srcs, E0, N);

    // ---- layer 1 ----
    mfma_gemm_k<128, false><<<dim3(gx, 2), b256, 0, stream>>>(
        x, nullptr, Wl1, bl1, Wr1, br1, XLh, XRh, N);
    fused128_k<true><<<(N + 15) / 16, b256, 0, stream>>>(XLh, XRh, att1, srcs, off, bias1, Cch, N);

    // ---- layer 2 ----
    mfma_gemm_k<64, true><<<dim3(gx, 1), b256, 0, stream>>>(
        nullptr, Cch, Wl2, bl2, Wr2, br2, XLh, XRh, N);
    fused64_k<false><<<(N + 31) / 32, b256, 0, stream>>>(XLh, XRh, att2, srcs, off, bias2, out, N);
}